// Round 3
// baseline (479.999 us; speedup 1.0000x reference)
//
#include <hip/hip_runtime.h>

// ---------------------------------------------------------------------------
// CrossAttention: out = softmax((x Wq)(ctx Wk)^T / sqrt(DH) + mask) (ctx Wv) Wo + bo
// B=16, NP=4096, NT=77 (padded to 96), QD=512, CD=768, H=8, DH=64, INNER=512
// fp16 MFMA (16x16x32), fp32 accumulate.
// R1: BK=64, XOR-swizzled LDS, XCD-aware block swizzle.        (443 -> 407 us)
// R2: explicit LDS double-buffer — REGRESSED (64KB LDS halved occupancy,
//     VALUBusy 20->8.5). Reverted.                              (407 -> 435 us)
// R3: single 32KB LDS + register prefetch (T14): A-operand global loads for
//     tile it+1 issued BEFORE MFMA(it), converted+ds_written after the
//     post-MFMA barrier. B stays global_load_lds (L2-resident weights).
//     Two barriers/iter, occupancy preserved, HBM latency hidden in regs.
// ---------------------------------------------------------------------------

typedef _Float16 half_t;
typedef _Float16 half8 __attribute__((ext_vector_type(8)));
typedef float f32x4 __attribute__((ext_vector_type(4)));
typedef unsigned int u32;

#define NB 16
#define NP 4096
#define NT 77
#define NTP 96
#define QD 512
#define CD 768
#define NH 8
#define DH 64
#define INNER 512
#define MKV (NB * NT)   // 1232

__device__ __forceinline__ void stage16(const void* g, void* l) {
    __builtin_amdgcn_global_load_lds((const __attribute__((address_space(1))) u32*)g,
                                     (__attribute__((address_space(3))) u32*)l, 16, 0, 0);
}

__device__ __forceinline__ f32x4 mfma16(half8 a, half8 b, f32x4 c) {
    return __builtin_amdgcn_mfma_f32_16x16x32_f16(a, b, c, 0, 0, 0);
}

// ---------------- paired transpose + fp32->fp16: out[n][k] = in[k][n] -------
__global__ __launch_bounds__(256) void kTrans2(const float* __restrict__ in0,
                                               const float* __restrict__ in1,
                                               half_t* __restrict__ out0,
                                               half_t* __restrict__ out1,
                                               int K, int N) {
    const float* in = blockIdx.z ? in1 : in0;
    half_t* out = blockIdx.z ? out1 : out0;
    __shared__ float tile[32][33];
    int tx = threadIdx.x & 31, ty = threadIdx.x >> 5;  // 32 x 8
    int kb = blockIdx.y * 32, nb = blockIdx.x * 32;
    for (int r = ty; r < 32; r += 8)
        tile[r][tx] = in[(size_t)(kb + r) * N + nb + tx];
    __syncthreads();
    for (int r = ty; r < 32; r += 8)
        out[(size_t)(nb + r) * K + kb + tx] = (half_t)tile[tx][r];
}

// ---------------- K/V projection GEMM, fused N=1024, BK=64 ------------------
// M=1232 (pad 1280, 64-row tiles), cols 0..511 -> K proj, 512..1023 -> V proj
// (R1 known-good single-buffer form)
__global__ __launch_bounds__(256) void kKVproj(const float* __restrict__ Ctx,
                                               const half_t* __restrict__ WkT,
                                               const half_t* __restrict__ WvT,
                                               half_t* __restrict__ Kp,
                                               half_t* __restrict__ VTp) {
    __shared__ alignas(16) half_t As[64 * 64];
    __shared__ alignas(16) half_t Bs[128 * 64];
    const int t = threadIdx.x, w = t >> 6, lane = t & 63;
    const int c0 = lane & 15, q4 = lane >> 4;
    const int rx = c0 & 7;
    const int m0 = blockIdx.y * 64;
    const int n0g = blockIdx.x * 128;
    const int z = n0g >= 512;
    const int n0 = n0g - z * 512;
    const half_t* WT = z ? WvT : WkT;

    f32x4 acc[4][2] = {};
    for (int k0 = 0; k0 < CD; k0 += 64) {
        for (int q = 0; q < 2; ++q) {
            int c = q * 256 + t;
            int row = c >> 3, ch = c & 7;
            int gr = m0 + row; if (gr > MKV - 1) gr = MKV - 1;
            const float* src = Ctx + (size_t)gr * CD + k0 + ch * 8;
            f32x4 f0 = *(const f32x4*)src;
            f32x4 f1 = *(const f32x4*)(src + 4);
            half8 hv;
            for (int e = 0; e < 4; ++e) { hv[e] = (half_t)f0[e]; hv[4 + e] = (half_t)f1[e]; }
            *(half8*)&As[row * 64 + ((ch ^ (row & 7)) * 8)] = hv;
        }
        for (int q = 0; q < 4; ++q) {
            int c = q * 256 + t;
            int row = c >> 3, k8 = c & 7;
            stage16(WT + (size_t)(n0 + row) * CD + k0 + (k8 ^ (row & 7)) * 8, &Bs[c * 8]);
        }
        __syncthreads();
        for (int ks = 0; ks < 2; ++ks) {
            int cx = ((ks * 4 + q4) ^ rx) * 8;
            half8 a[4], b[2];
            for (int i = 0; i < 4; ++i)
                a[i] = *(const half8*)&As[(16 * i + c0) * 64 + cx];
            for (int j = 0; j < 2; ++j)
                b[j] = *(const half8*)&Bs[(w * 32 + 16 * j + c0) * 64 + cx];
            for (int i = 0; i < 4; ++i)
                for (int j = 0; j < 2; ++j)
                    acc[i][j] = mfma16(a[i], b[j], acc[i][j]);
        }
        __syncthreads();
    }
    for (int i = 0; i < 4; ++i)
        for (int j = 0; j < 2; ++j)
            for (int r = 0; r < 4; ++r) {
                int row = m0 + 16 * i + q4 * 4 + r;
                if (row >= MKV) continue;
                int col = n0 + w * 32 + 16 * j + c0;
                int b = row / NT, tt = row - b * NT;
                int h = col >> 6, d = col & 63;
                half_t v = (half_t)acc[i][j][r];
                if (!z) Kp[(((size_t)b * NH + h) * NTP + tt) * DH + d] = v;
                else    VTp[(((size_t)b * NH + h) * DH + d) * NTP + tt] = v;
            }
}

// ---------------- Q projection: Q = x(fp32) @ WqT^T  (M=65536,K=512,N=512) --
// BK=64, XOR-swizzled LDS, XCD swizzle, single 32KB LDS + A-reg prefetch
__global__ __launch_bounds__(256) void kQproj(const float* __restrict__ X,
                                              const half_t* __restrict__ WqT,
                                              half_t* __restrict__ Q) {
    __shared__ alignas(16) half_t As[128 * 64];
    __shared__ alignas(16) half_t Bs[128 * 64];
    const int t = threadIdx.x, w = t >> 6, lane = t & 63;
    const int c0 = lane & 15, q4 = lane >> 4;
    const int rx = c0 & 7;
    const int wm = w & 1, wn = w >> 1;
    const int bid = blockIdx.x;
    const int wid = (bid & 7) * 256 + (bid >> 3);   // XCD k gets wids [k*256,(k+1)*256)
    const int m0 = (wid >> 2) * 128, n0 = (wid & 3) * 128;

    f32x4 pa[4][2];
    auto issueA = [&](int k0) {
        for (int q = 0; q < 4; ++q) {
            int c = q * 256 + t;
            int row = c >> 3, ch = c & 7;
            const float* src = X + (size_t)(m0 + row) * QD + k0 + ch * 8;
            pa[q][0] = *(const f32x4*)src;
            pa[q][1] = *(const f32x4*)(src + 4);
        }
    };
    auto writeA = [&]() {
        for (int q = 0; q < 4; ++q) {
            int c = q * 256 + t;
            int row = c >> 3, ch = c & 7;
            half8 hv;
            for (int e = 0; e < 4; ++e) { hv[e] = (half_t)pa[q][0][e]; hv[4 + e] = (half_t)pa[q][1][e]; }
            *(half8*)&As[row * 64 + ((ch ^ (row & 7)) * 8)] = hv;
        }
    };
    auto stageB = [&](int k0) {
        for (int q = 0; q < 4; ++q) {
            int c = q * 256 + t;
            int row = c >> 3, k8 = c & 7;
            stage16(WqT + (size_t)(n0 + row) * QD + k0 + (k8 ^ (row & 7)) * 8, &Bs[c * 8]);
        }
    };

    f32x4 acc[4][4] = {};
    issueA(0);
    stageB(0);
    writeA();
    __syncthreads();          // drains B gload_lds + A ds_writes
    issueA(64);               // tile 1 in flight during tile 0 compute
    for (int it = 0; it < 8; ++it) {
        for (int ks = 0; ks < 2; ++ks) {
            int cx = ((ks * 4 + q4) ^ rx) * 8;
            half8 a[4];
            for (int i = 0; i < 4; ++i)
                a[i] = *(const half8*)&As[(wm * 64 + 16 * i + c0) * 64 + cx];
            for (int j = 0; j < 4; ++j) {
                half8 bv = *(const half8*)&Bs[(wn * 64 + 16 * j + c0) * 64 + cx];
                for (int i = 0; i < 4; ++i)
                    acc[i][j] = mfma16(a[i], bv, acc[i][j]);
            }
        }
        if (it < 7) {
            __syncthreads();                      // all waves done reading tile it
            writeA();                             // tile it+1 (loads issued 1 iter ago)
            stageB((it + 1) * 64);                // L2-resident weights
            if (it < 6) issueA((it + 2) * 64);    // next A loads into regs
            __syncthreads();                      // writes visible
        }
    }
    for (int i = 0; i < 4; ++i)
        for (int j = 0; j < 4; ++j)
            for (int r = 0; r < 4; ++r) {
                int row = m0 + wm * 64 + 16 * i + q4 * 4 + r;
                int col = n0 + wn * 64 + 16 * j + c0;
                Q[(size_t)row * INNER + col] = (half_t)acc[i][j][r];
            }
}

// ---------------- fused attention per (qtile=128, h, b); AO overwrites Q ----
__global__ __launch_bounds__(256) void kAttn(half_t* __restrict__ Q,
                                             const half_t* __restrict__ Kp,
                                             const half_t* __restrict__ VTp,
                                             const int* __restrict__ mask) {
    __shared__ alignas(16) half_t Qs[128 * 104];   // stride 104; reused as P
    __shared__ alignas(16) half_t Ks[NTP * 72];    // stride 72
    __shared__ alignas(16) half_t VTs[DH * 104];   // stride 104
    const int t = threadIdx.x, w = t >> 6, lane = t & 63;
    const int c0 = lane & 15, q4 = lane >> 4;
    const int qt = blockIdx.x, h = blockIdx.y, b = blockIdx.z;
    const int q0 = qt * 128;
    const size_t qbase = ((size_t)b * NP + q0) * INNER + h * DH;

    for (int q = 0; q < 4; ++q) {
        int c = q * 256 + t, m = c >> 3, k8 = (c & 7) * 8;
        *(uint4*)&Qs[m * 104 + k8] = *(const uint4*)(Q + qbase + (size_t)m * INNER + k8);
    }
    const half_t* Kh = Kp + ((size_t)b * NH + h) * NTP * DH;
    for (int q = 0; q < 3; ++q) {
        int c = q * 256 + t, r = c >> 3, k8 = (c & 7) * 8;
        *(uint4*)&Ks[r * 72 + k8] = *(const uint4*)(Kh + r * DH + k8);
    }
    const half_t* Vh = VTp + ((size_t)b * NH + h) * DH * NTP;
    for (int q = 0; q < 3; ++q) {
        int c = q * 256 + t, r = c / 12, t8 = (c % 12) * 8;
        *(uint4*)&VTs[r * 104 + t8] = *(const uint4*)(Vh + r * NTP + t8);
    }
    __syncthreads();

    const int r0 = w * 32;
    f32x4 sacc[2][6] = {};
    __builtin_amdgcn_s_setprio(1);
    for (int ks = 0; ks < 2; ++ks) {
        half8 a0 = *(const half8*)&Qs[(r0 + c0) * 104 + ks * 32 + q4 * 8];
        half8 a1 = *(const half8*)&Qs[(r0 + 16 + c0) * 104 + ks * 32 + q4 * 8];
        for (int j = 0; j < 6; ++j) {
            half8 bv = *(const half8*)&Ks[(16 * j + c0) * 72 + ks * 32 + q4 * 8];
            sacc[0][j] = mfma16(a0, bv, sacc[0][j]);
            sacc[1][j] = mfma16(a1, bv, sacc[1][j]);
        }
    }
    __builtin_amdgcn_s_setprio(0);

    for (int i = 0; i < 2; ++i)
        for (int r = 0; r < 4; ++r) {
            int qrow = r0 + 16 * i + q4 * 4 + r;
            const int* mrow = mask + ((size_t)b * NP + q0 + qrow) * NT;
            float sv[6];
            for (int j = 0; j < 6; ++j) {
                int tt = 16 * j + c0;
                float s = sacc[i][j][r] * 0.125f;
                bool valid = (tt < NT) && (mrow[tt < NT ? tt : NT - 1] != 0);
                sv[j] = valid ? s : -1e30f;
            }
            float mx = sv[0];
            for (int j = 1; j < 6; ++j) mx = fmaxf(mx, sv[j]);
            for (int d = 1; d < 16; d <<= 1) mx = fmaxf(mx, __shfl_xor(mx, d));
            float pv[6], sum = 0.f;
            for (int j = 0; j < 6; ++j) { pv[j] = __expf(sv[j] - mx); sum += pv[j]; }
            for (int d = 1; d < 16; d <<= 1) sum += __shfl_xor(sum, d);
            float inv = 1.0f / sum;
            for (int j = 0; j < 6; ++j)
                Qs[qrow * 104 + 16 * j + c0] = (half_t)(pv[j] * inv);
        }
    // no barrier needed: each wave reads only its own 32 Qs rows for PV, and
    // LDS ops within a wave are processed in order; VTs was synced above.

    f32x4 oacc[2][4] = {};
    __builtin_amdgcn_s_setprio(1);
    for (int ks = 0; ks < 3; ++ks) {
        half8 a0 = *(const half8*)&Qs[(r0 + c0) * 104 + ks * 32 + q4 * 8];
        half8 a1 = *(const half8*)&Qs[(r0 + 16 + c0) * 104 + ks * 32 + q4 * 8];
        for (int j = 0; j < 4; ++j) {
            half8 bv = *(const half8*)&VTs[(16 * j + c0) * 104 + ks * 32 + q4 * 8];
            oacc[0][j] = mfma16(a0, bv, oacc[0][j]);
            oacc[1][j] = mfma16(a1, bv, oacc[1][j]);
        }
    }
    __builtin_amdgcn_s_setprio(0);
    for (int i = 0; i < 2; ++i)
        for (int j = 0; j < 4; ++j)
            for (int r = 0; r < 4; ++r) {
                int qrow = r0 + 16 * i + q4 * 4 + r;
                int d = 16 * j + c0;
                Q[qbase + (size_t)qrow * INNER + d] = (half_t)oacc[i][j][r];
            }
}

// ---------------- output projection: out = AO @ WoT^T + bo (fp32 out) -------
// BK=64, XOR-swizzled LDS, XCD swizzle, single 32KB LDS + A-reg prefetch
__global__ __launch_bounds__(256) void kOproj(const half_t* __restrict__ AO,
                                              const half_t* __restrict__ WoT,
                                              const float* __restrict__ bo,
                                              float* __restrict__ out) {
    __shared__ alignas(16) half_t As[128 * 64];
    __shared__ alignas(16) half_t Bs[128 * 64];
    const int t = threadIdx.x, w = t >> 6, lane = t & 63;
    const int c0 = lane & 15, q4 = lane >> 4;
    const int rx = c0 & 7;
    const int wm = w & 1, wn = w >> 1;
    const int bid = blockIdx.x;
    const int wid = (bid & 7) * 256 + (bid >> 3);
    const int m0 = (wid >> 2) * 128, n0 = (wid & 3) * 128;

    float bj[4];
    for (int j = 0; j < 4; ++j) bj[j] = bo[n0 + wn * 64 + 16 * j + c0];

    uint4 pa[4];
    auto issueA = [&](int k0) {
        for (int q = 0; q < 4; ++q) {
            int c = q * 256 + t;
            int row = c >> 3, ch = c & 7;
            pa[q] = *(const uint4*)(AO + (size_t)(m0 + row) * INNER + k0 + ch * 8);
        }
    };
    auto writeA = [&]() {
        for (int q = 0; q < 4; ++q) {
            int c = q * 256 + t;
            int row = c >> 3, ch = c & 7;
            *(uint4*)&As[row * 64 + ((ch ^ (row & 7)) * 8)] = pa[q];
        }
    };
    auto stageB = [&](int k0) {
        for (int q = 0; q < 4; ++q) {
            int c = q * 256 + t;
            int row = c >> 3, k8 = c & 7;
            stage16(WoT + (size_t)(n0 + row) * INNER + k0 + (k8 ^ (row & 7)) * 8, &Bs[c * 8]);
        }
    };

    f32x4 acc[4][4] = {};
    issueA(0);
    stageB(0);
    writeA();
    __syncthreads();
    issueA(64);
    for (int it = 0; it < 8; ++it) {
        for (int ks = 0; ks < 2; ++ks) {
            int cx = ((ks * 4 + q4) ^ rx) * 8;
            half8 a[4];
            for (int i = 0; i < 4; ++i)
                a[i] = *(const half8*)&As[(wm * 64 + 16 * i + c0) * 64 + cx];
            for (int j = 0; j < 4; ++j) {
                half8 bv = *(const half8*)&Bs[(wn * 64 + 16 * j + c0) * 64 + cx];
                for (int i = 0; i < 4; ++i)
                    acc[i][j] = mfma16(a[i], bv, acc[i][j]);
            }
        }
        if (it < 7) {
            __syncthreads();
            writeA();
            stageB((it + 1) * 64);
            if (it < 6) issueA((it + 2) * 64);
            __syncthreads();
        }
    }
    for (int i = 0; i < 4; ++i)
        for (int j = 0; j < 4; ++j)
            for (int r = 0; r < 4; ++r) {
                int row = m0 + wm * 64 + 16 * i + q4 * 4 + r;
                int col = n0 + wn * 64 + 16 * j + c0;
                out[(size_t)row * QD + col] = acc[i][j][r] + bj[j];
            }
}

// ---------------------------------------------------------------------------
extern "C" void kernel_launch(void* const* d_in, const int* in_sizes, int n_in,
                              void* d_out, int out_size, void* d_ws, size_t ws_size,
                              hipStream_t stream) {
    const float* x   = (const float*)d_in[0];
    const float* ctx = (const float*)d_in[1];
    const int*   msk = (const int*)d_in[2];
    const float* Wq  = (const float*)d_in[3];
    const float* Wk  = (const float*)d_in[4];
    const float* Wv  = (const float*)d_in[5];
    const float* Wo  = (const float*)d_in[6];
    const float* bo  = (const float*)d_in[7];
    float* out = (float*)d_out;

    half_t* Qws = (half_t*)d_ws;                       // 65536*512
    half_t* WqT = Qws + (size_t)NB * NP * INNER;       // 512*512
    half_t* WoT = WqT + (size_t)QD * INNER;            // 512*512
    half_t* WkT = WoT + (size_t)INNER * QD;            // 512*768
    half_t* WvT = WkT + (size_t)INNER * CD;            // 512*768
    half_t* Kp  = WvT + (size_t)INNER * CD;            // 16*8*96*64
    half_t* VTp = Kp + (size_t)NB * NH * NTP * DH;     // 16*8*64*96

    kTrans2<<<dim3(INNER / 32, QD / 32, 2), 256, 0, stream>>>(Wq, Wo, WqT, WoT, QD, INNER);
    kTrans2<<<dim3(INNER / 32, CD / 32, 2), 256, 0, stream>>>(Wk, Wv, WkT, WvT, CD, INNER);
    hipMemsetAsync(Kp, 0, (size_t)NB * NH * (NTP * DH + DH * NTP) * sizeof(half_t), stream);
    kKVproj<<<dim3(8, 20), 256, 0, stream>>>(ctx, WkT, WvT, Kp, VTp);
    kQproj<<<dim3(2048), 256, 0, stream>>>(x, WqT, Qws);
    kAttn<<<dim3(NP / 128, NH, NB), 256, 0, stream>>>(Qws, Kp, VTp, msk);
    kOproj<<<dim3(2048), 256, 0, stream>>>(Qws, WoT, bo, out);
}

// Round 4
// 405.384 us; speedup vs baseline: 1.1841x; 1.1841x over previous
//
#include <hip/hip_runtime.h>

// ---------------------------------------------------------------------------
// CrossAttention: out = softmax((x Wq)(ctx Wk)^T / sqrt(DH) + mask) (ctx Wv) Wo + bo
// B=16, NP=4096, NT=77 (padded to 96), QD=512, CD=768, H=8, DH=64, INNER=512
// fp16 MFMA (16x16x32), fp32 accumulate.
// R1: BK=64, XOR-swizzled LDS, XCD-aware block swizzle.        (443 -> 407 us)
// R2: explicit LDS double-buffer — REGRESSED (occupancy).       (407 -> 435 us)
// R3: register prefetch pipeline — REGRESSED (same lesson:
//     source-level pipelining loses to implicit wave overlap).  (435 -> 480 us)
// R4: revert to R1 structure. Surgical fixes only:
//     - kOproj/kQproj epilogues: in-quad shfl transpose -> vectorized stores
//       (fp32 f32x4 / half4), targeting kOproj's 215MB-vs-134MB write ampl.
//     - kMaskPack: mask -> 2x u64 bits per (b,row); kAttn does one 16B
//       broadcast load + bit test instead of 48 scattered int loads.
//     - kAttn: drop always-masked j=5 score block (cols 80..95 >= NT=77).
// ---------------------------------------------------------------------------

typedef _Float16 half_t;
typedef _Float16 half8 __attribute__((ext_vector_type(8)));
typedef _Float16 half4_t __attribute__((ext_vector_type(4)));
typedef float f32x4 __attribute__((ext_vector_type(4)));
typedef unsigned int u32;
typedef unsigned long long u64;

#define NB 16
#define NP 4096
#define NT 77
#define NTP 96
#define QD 512
#define CD 768
#define NH 8
#define DH 64
#define INNER 512
#define MKV (NB * NT)   // 1232

__device__ __forceinline__ void stage16(const void* g, void* l) {
    __builtin_amdgcn_global_load_lds((const __attribute__((address_space(1))) u32*)g,
                                     (__attribute__((address_space(3))) u32*)l, 16, 0, 0);
}

__device__ __forceinline__ f32x4 mfma16(half8 a, half8 b, f32x4 c) {
    return __builtin_amdgcn_mfma_f32_16x16x32_f16(a, b, c, 0, 0, 0);
}

// in-quad 4x4 transpose: lane cq in [0,4) holds v[r]=M[r][cq]; after, v[e]=M[cq][e]
__device__ __forceinline__ void quadT(float& v0, float& v1, float& v2, float& v3, int cq) {
    float s, rr;
    s = (cq & 1) ? v0 : v1; rr = __shfl_xor(s, 1); if (cq & 1) v0 = rr; else v1 = rr;
    s = (cq & 1) ? v2 : v3; rr = __shfl_xor(s, 1); if (cq & 1) v2 = rr; else v3 = rr;
    s = (cq & 2) ? v0 : v2; rr = __shfl_xor(s, 2); if (cq & 2) v0 = rr; else v2 = rr;
    s = (cq & 2) ? v1 : v3; rr = __shfl_xor(s, 2); if (cq & 2) v1 = rr; else v3 = rr;
}

// ---------------- paired transpose + fp32->fp16: out[n][k] = in[k][n] -------
__global__ __launch_bounds__(256) void kTrans2(const float* __restrict__ in0,
                                               const float* __restrict__ in1,
                                               half_t* __restrict__ out0,
                                               half_t* __restrict__ out1,
                                               int K, int N) {
    const float* in = blockIdx.z ? in1 : in0;
    half_t* out = blockIdx.z ? out1 : out0;
    __shared__ float tile[32][33];
    int tx = threadIdx.x & 31, ty = threadIdx.x >> 5;  // 32 x 8
    int kb = blockIdx.y * 32, nb = blockIdx.x * 32;
    for (int r = ty; r < 32; r += 8)
        tile[r][tx] = in[(size_t)(kb + r) * N + nb + tx];
    __syncthreads();
    for (int r = ty; r < 32; r += 8)
        out[(size_t)(nb + r) * K + kb + tx] = (half_t)tile[tx][r];
}

// ---------------- mask -> bitmask: 2x u64 per (b,row) ----------------------
__global__ __launch_bounds__(256) void kMaskPack(const int* __restrict__ mask,
                                                 ulonglong2* __restrict__ mpk) {
    int row = blockIdx.x * 4 + (threadIdx.x >> 6);   // one wave per row
    int lane = threadIdx.x & 63;
    const int* mr = mask + (size_t)row * NT;
    int v1 = mr[lane];                                // t = 0..63
    u64 lo = __ballot(v1 != 0);
    int v2 = (lane < NT - 64) ? mr[64 + lane] : 0;    // t = 64..76
    u64 hi = __ballot(v2 != 0);
    if (lane == 0) { mpk[row].x = lo; mpk[row].y = hi; }
}

// ---------------- K/V projection GEMM, fused N=1024, BK=64 ------------------
// M=1232 (pad 1280, 64-row tiles), cols 0..511 -> K proj, 512..1023 -> V proj
__global__ __launch_bounds__(256) void kKVproj(const float* __restrict__ Ctx,
                                               const half_t* __restrict__ WkT,
                                               const half_t* __restrict__ WvT,
                                               half_t* __restrict__ Kp,
                                               half_t* __restrict__ VTp) {
    __shared__ alignas(16) half_t As[64 * 64];
    __shared__ alignas(16) half_t Bs[128 * 64];
    const int t = threadIdx.x, w = t >> 6, lane = t & 63;
    const int c0 = lane & 15, q4 = lane >> 4;
    const int rx = c0 & 7;
    const int m0 = blockIdx.y * 64;
    const int n0g = blockIdx.x * 128;
    const int z = n0g >= 512;
    const int n0 = n0g - z * 512;
    const half_t* WT = z ? WvT : WkT;

    f32x4 acc[4][2] = {};
    for (int k0 = 0; k0 < CD; k0 += 64) {
        for (int q = 0; q < 2; ++q) {
            int c = q * 256 + t;
            int row = c >> 3, ch = c & 7;
            int gr = m0 + row; if (gr > MKV - 1) gr = MKV - 1;
            const float* src = Ctx + (size_t)gr * CD + k0 + ch * 8;
            f32x4 f0 = *(const f32x4*)src;
            f32x4 f1 = *(const f32x4*)(src + 4);
            half8 hv;
            for (int e = 0; e < 4; ++e) { hv[e] = (half_t)f0[e]; hv[4 + e] = (half_t)f1[e]; }
            *(half8*)&As[row * 64 + ((ch ^ (row & 7)) * 8)] = hv;
        }
        for (int q = 0; q < 4; ++q) {
            int c = q * 256 + t;
            int row = c >> 3, k8 = c & 7;
            stage16(WT + (size_t)(n0 + row) * CD + k0 + (k8 ^ (row & 7)) * 8, &Bs[c * 8]);
        }
        __syncthreads();
        for (int ks = 0; ks < 2; ++ks) {
            int cx = ((ks * 4 + q4) ^ rx) * 8;
            half8 a[4], b[2];
            for (int i = 0; i < 4; ++i)
                a[i] = *(const half8*)&As[(16 * i + c0) * 64 + cx];
            for (int j = 0; j < 2; ++j)
                b[j] = *(const half8*)&Bs[(w * 32 + 16 * j + c0) * 64 + cx];
            for (int i = 0; i < 4; ++i)
                for (int j = 0; j < 2; ++j)
                    acc[i][j] = mfma16(a[i], b[j], acc[i][j]);
        }
        __syncthreads();
    }
    for (int i = 0; i < 4; ++i)
        for (int j = 0; j < 2; ++j)
            for (int r = 0; r < 4; ++r) {
                int row = m0 + 16 * i + q4 * 4 + r;
                if (row >= MKV) continue;
                int col = n0 + w * 32 + 16 * j + c0;
                int b = row / NT, tt = row - b * NT;
                int h = col >> 6, d = col & 63;
                half_t v = (half_t)acc[i][j][r];
                if (!z) Kp[(((size_t)b * NH + h) * NTP + tt) * DH + d] = v;
                else    VTp[(((size_t)b * NH + h) * DH + d) * NTP + tt] = v;
            }
}

// ---------------- Q projection: Q = x(fp32) @ WqT^T  (M=65536,K=512,N=512) --
// BK=64, XOR-swizzled LDS, XCD swizzle, R1 single-buffer loop
__global__ __launch_bounds__(256) void kQproj(const float* __restrict__ X,
                                              const half_t* __restrict__ WqT,
                                              half_t* __restrict__ Q) {
    __shared__ alignas(16) half_t As[128 * 64];
    __shared__ alignas(16) half_t Bs[128 * 64];
    const int t = threadIdx.x, w = t >> 6, lane = t & 63;
    const int c0 = lane & 15, q4 = lane >> 4;
    const int rx = c0 & 7;
    const int wm = w & 1, wn = w >> 1;
    const int bid = blockIdx.x;
    const int wid = (bid & 7) * 256 + (bid >> 3);   // XCD k gets wids [k*256,(k+1)*256)
    const int m0 = (wid >> 2) * 128, n0 = (wid & 3) * 128;

    f32x4 acc[4][4] = {};
    for (int k0 = 0; k0 < QD; k0 += 64) {
        for (int q = 0; q < 4; ++q) {
            int c = q * 256 + t;
            int row = c >> 3, ch = c & 7;
            const float* src = X + (size_t)(m0 + row) * QD + k0 + ch * 8;
            f32x4 f0 = *(const f32x4*)src;
            f32x4 f1 = *(const f32x4*)(src + 4);
            half8 hv;
            for (int e = 0; e < 4; ++e) { hv[e] = (half_t)f0[e]; hv[4 + e] = (half_t)f1[e]; }
            *(half8*)&As[row * 64 + ((ch ^ (row & 7)) * 8)] = hv;
        }
        for (int q = 0; q < 4; ++q) {
            int c = q * 256 + t;
            int row = c >> 3, k8 = c & 7;
            stage16(WqT + (size_t)(n0 + row) * QD + k0 + (k8 ^ (row & 7)) * 8, &Bs[c * 8]);
        }
        __syncthreads();
        for (int ks = 0; ks < 2; ++ks) {
            int cx = ((ks * 4 + q4) ^ rx) * 8;
            half8 a[4];
            for (int i = 0; i < 4; ++i)
                a[i] = *(const half8*)&As[(wm * 64 + 16 * i + c0) * 64 + cx];
            for (int j = 0; j < 4; ++j) {
                half8 bv = *(const half8*)&Bs[(wn * 64 + 16 * j + c0) * 64 + cx];
                for (int i = 0; i < 4; ++i)
                    acc[i][j] = mfma16(a[i], bv, acc[i][j]);
            }
        }
        __syncthreads();
    }
    // epilogue: in-quad transpose -> half4 (8B) stores, 16 instrs/thread
    const int cq = c0 & 3;
    for (int i = 0; i < 4; ++i)
        for (int j = 0; j < 4; ++j) {
            float v0 = acc[i][j][0], v1 = acc[i][j][1], v2 = acc[i][j][2], v3 = acc[i][j][3];
            quadT(v0, v1, v2, v3, cq);
            int row = m0 + wm * 64 + 16 * i + q4 * 4 + cq;
            int col = n0 + wn * 64 + 16 * j + (c0 & 12);
            half4_t hv = {(half_t)v0, (half_t)v1, (half_t)v2, (half_t)v3};
            *(half4_t*)&Q[(size_t)row * INNER + col] = hv;
        }
}

// ---------------- fused attention per (qtile=128, h, b); AO overwrites Q ----
__global__ __launch_bounds__(256) void kAttn(half_t* __restrict__ Q,
                                             const half_t* __restrict__ Kp,
                                             const half_t* __restrict__ VTp,
                                             const ulonglong2* __restrict__ mpk) {
    __shared__ alignas(16) half_t Qs[128 * 104];   // stride 104; reused as P
    __shared__ alignas(16) half_t Ks[NTP * 72];    // stride 72
    __shared__ alignas(16) half_t VTs[DH * 104];   // stride 104
    const int t = threadIdx.x, w = t >> 6, lane = t & 63;
    const int c0 = lane & 15, q4 = lane >> 4;
    const int qt = blockIdx.x, h = blockIdx.y, b = blockIdx.z;
    const int q0 = qt * 128;
    const size_t qbase = ((size_t)b * NP + q0) * INNER + h * DH;

    for (int q = 0; q < 4; ++q) {
        int c = q * 256 + t, m = c >> 3, k8 = (c & 7) * 8;
        *(uint4*)&Qs[m * 104 + k8] = *(const uint4*)(Q + qbase + (size_t)m * INNER + k8);
    }
    const half_t* Kh = Kp + ((size_t)b * NH + h) * NTP * DH;
    for (int q = 0; q < 3; ++q) {
        int c = q * 256 + t, r = c >> 3, k8 = (c & 7) * 8;
        *(uint4*)&Ks[r * 72 + k8] = *(const uint4*)(Kh + r * DH + k8);
    }
    const half_t* Vh = VTp + ((size_t)b * NH + h) * DH * NTP;
    for (int q = 0; q < 3; ++q) {
        int c = q * 256 + t, r = c / 12, t8 = (c % 12) * 8;
        *(uint4*)&VTs[r * 104 + t8] = *(const uint4*)(Vh + r * NTP + t8);
    }
    __syncthreads();

    const int r0 = w * 32;
    // QK^T: only j<5 (cols 80..95 are >= NT, always masked)
    f32x4 sacc[2][5] = {};
    __builtin_amdgcn_s_setprio(1);
    for (int ks = 0; ks < 2; ++ks) {
        half8 a0 = *(const half8*)&Qs[(r0 + c0) * 104 + ks * 32 + q4 * 8];
        half8 a1 = *(const half8*)&Qs[(r0 + 16 + c0) * 104 + ks * 32 + q4 * 8];
        for (int j = 0; j < 5; ++j) {
            half8 bv = *(const half8*)&Ks[(16 * j + c0) * 72 + ks * 32 + q4 * 8];
            sacc[0][j] = mfma16(a0, bv, sacc[0][j]);
            sacc[1][j] = mfma16(a1, bv, sacc[1][j]);
        }
    }
    __builtin_amdgcn_s_setprio(0);

    for (int i = 0; i < 2; ++i)
        for (int r = 0; r < 4; ++r) {
            int qrow = r0 + 16 * i + q4 * 4 + r;
            ulonglong2 mb = mpk[(size_t)b * NP + q0 + qrow];
            float sv[5];
            for (int j = 0; j < 5; ++j) {
                u64 mwd = (j < 4) ? mb.x : mb.y;
                int sh = (j < 4) ? (16 * j + c0) : c0;  // bits >= 13 of hi are 0
                float s = sacc[i][j][r] * 0.125f;
                sv[j] = ((mwd >> sh) & 1ull) ? s : -1e30f;
            }
            float mx = sv[0];
            for (int j = 1; j < 5; ++j) mx = fmaxf(mx, sv[j]);
            for (int d = 1; d < 16; d <<= 1) mx = fmaxf(mx, __shfl_xor(mx, d));
            float pv[5], sum = 0.f;
            for (int j = 0; j < 5; ++j) { pv[j] = __expf(sv[j] - mx); sum += pv[j]; }
            for (int d = 1; d < 16; d <<= 1) sum += __shfl_xor(sum, d);
            float inv = 1.0f / sum;
            for (int j = 0; j < 5; ++j)
                Qs[qrow * 104 + 16 * j + c0] = (half_t)(pv[j] * inv);
            Qs[qrow * 104 + 80 + c0] = (half_t)0.f;   // P cols 80..95 = 0 for PV
        }
    // no barrier needed: each wave reads only its own 32 Qs rows for PV, and
    // LDS ops within a wave are processed in order; VTs was synced above.

    f32x4 oacc[2][4] = {};
    __builtin_amdgcn_s_setprio(1);
    for (int ks = 0; ks < 3; ++ks) {
        half8 a0 = *(const half8*)&Qs[(r0 + c0) * 104 + ks * 32 + q4 * 8];
        half8 a1 = *(const half8*)&Qs[(r0 + 16 + c0) * 104 + ks * 32 + q4 * 8];
        for (int j = 0; j < 4; ++j) {
            half8 bv = *(const half8*)&VTs[(16 * j + c0) * 104 + ks * 32 + q4 * 8];
            oacc[0][j] = mfma16(a0, bv, oacc[0][j]);
            oacc[1][j] = mfma16(a1, bv, oacc[1][j]);
        }
    }
    __builtin_amdgcn_s_setprio(0);
    for (int i = 0; i < 2; ++i)
        for (int j = 0; j < 4; ++j)
            for (int r = 0; r < 4; ++r) {
                int qrow = r0 + 16 * i + q4 * 4 + r;
                int d = 16 * j + c0;
                Q[qbase + (size_t)qrow * INNER + d] = (half_t)oacc[i][j][r];
            }
}

// ---------------- output projection: out = AO @ WoT^T + bo (fp32 out) -------
// BK=64, XOR-swizzled LDS, XCD swizzle, R1 single-buffer loop
__global__ __launch_bounds__(256) void kOproj(const half_t* __restrict__ AO,
                                              const half_t* __restrict__ WoT,
                                              const float* __restrict__ bo,
                                              float* __restrict__ out) {
    __shared__ alignas(16) half_t As[128 * 64];
    __shared__ alignas(16) half_t Bs[128 * 64];
    const int t = threadIdx.x, w = t >> 6, lane = t & 63;
    const int c0 = lane & 15, q4 = lane >> 4;
    const int rx = c0 & 7;
    const int wm = w & 1, wn = w >> 1;
    const int bid = blockIdx.x;
    const int wid = (bid & 7) * 256 + (bid >> 3);
    const int m0 = (wid >> 2) * 128, n0 = (wid & 3) * 128;

    f32x4 bq[4];
    for (int j = 0; j < 4; ++j)
        bq[j] = *(const f32x4*)&bo[n0 + wn * 64 + 16 * j + (c0 & 12)];

    f32x4 acc[4][4] = {};
    for (int k0 = 0; k0 < INNER; k0 += 64) {
        for (int q = 0; q < 4; ++q) {
            int c = q * 256 + t;
            int row = c >> 3, k8 = c & 7;
            stage16(AO + (size_t)(m0 + row) * INNER + k0 + (k8 ^ (row & 7)) * 8, &As[c * 8]);
        }
        for (int q = 0; q < 4; ++q) {
            int c = q * 256 + t;
            int row = c >> 3, k8 = c & 7;
            stage16(WoT + (size_t)(n0 + row) * INNER + k0 + (k8 ^ (row & 7)) * 8, &Bs[c * 8]);
        }
        __syncthreads();
        for (int ks = 0; ks < 2; ++ks) {
            int cx = ((ks * 4 + q4) ^ rx) * 8;
            half8 a[4];
            for (int i = 0; i < 4; ++i)
                a[i] = *(const half8*)&As[(wm * 64 + 16 * i + c0) * 64 + cx];
            for (int j = 0; j < 4; ++j) {
                half8 bv = *(const half8*)&Bs[(wn * 64 + 16 * j + c0) * 64 + cx];
                for (int i = 0; i < 4; ++i)
                    acc[i][j] = mfma16(a[i], bv, acc[i][j]);
            }
        }
        __syncthreads();
    }
    // epilogue: in-quad transpose -> f32x4 (16B) stores + bias, 16 instrs/thread
    const int cq = c0 & 3;
    for (int i = 0; i < 4; ++i)
        for (int j = 0; j < 4; ++j) {
            float v0 = acc[i][j][0], v1 = acc[i][j][1], v2 = acc[i][j][2], v3 = acc[i][j][3];
            quadT(v0, v1, v2, v3, cq);
            int row = m0 + wm * 64 + 16 * i + q4 * 4 + cq;
            int col = n0 + wn * 64 + 16 * j + (c0 & 12);
            f32x4 o = {v0 + bq[j][0], v1 + bq[j][1], v2 + bq[j][2], v3 + bq[j][3]};
            *(f32x4*)&out[(size_t)row * QD + col] = o;
        }
}

// ---------------------------------------------------------------------------
extern "C" void kernel_launch(void* const* d_in, const int* in_sizes, int n_in,
                              void* d_out, int out_size, void* d_ws, size_t ws_size,
                              hipStream_t stream) {
    const float* x   = (const float*)d_in[0];
    const float* ctx = (const float*)d_in[1];
    const int*   msk = (const int*)d_in[2];
    const float* Wq  = (const float*)d_in[3];
    const float* Wk  = (const float*)d_in[4];
    const float* Wv  = (const float*)d_in[5];
    const float* Wo  = (const float*)d_in[6];
    const float* bo  = (const float*)d_in[7];
    float* out = (float*)d_out;

    half_t* Qws = (half_t*)d_ws;                       // 65536*512
    half_t* WqT = Qws + (size_t)NB * NP * INNER;       // 512*512
    half_t* WoT = WqT + (size_t)QD * INNER;            // 512*512
    half_t* WkT = WoT + (size_t)INNER * QD;            // 512*768
    half_t* WvT = WkT + (size_t)INNER * CD;            // 512*768
    half_t* Kp  = WvT + (size_t)INNER * CD;            // 16*8*96*64
    half_t* VTp = Kp + (size_t)NB * NH * NTP * DH;     // 16*8*64*96
    ulonglong2* mpk = (ulonglong2*)(VTp + (size_t)NB * NH * DH * NTP);  // 65536*16B

    kTrans2<<<dim3(INNER / 32, QD / 32, 2), 256, 0, stream>>>(Wq, Wo, WqT, WoT, QD, INNER);
    kTrans2<<<dim3(INNER / 32, CD / 32, 2), 256, 0, stream>>>(Wk, Wv, WkT, WvT, CD, INNER);
    kMaskPack<<<dim3(NB * NP / 4), 256, 0, stream>>>(msk, mpk);
    hipMemsetAsync(Kp, 0, (size_t)NB * NH * (NTP * DH + DH * NTP) * sizeof(half_t), stream);
    kKVproj<<<dim3(8, 20), 256, 0, stream>>>(ctx, WkT, WvT, Kp, VTp);
    kQproj<<<dim3(2048), 256, 0, stream>>>(x, WqT, Qws);
    kAttn<<<dim3(NP / 128, NH, NB), 256, 0, stream>>>(Qws, Kp, VTp, mpk);
    kOproj<<<dim3(2048), 256, 0, stream>>>(Qws, WoT, bo, out);
}